// Round 10
// baseline (239.098 us; speedup 1.0000x reference)
//
#include <hip/hip_runtime.h>

typedef __bf16 bf16;
typedef __bf16 bf16x8 __attribute__((ext_vector_type(8)));
typedef float f32x4 __attribute__((ext_vector_type(4)));
typedef unsigned u32x2 __attribute__((ext_vector_type(2)));

static constexpr int NB = 4;       // batch
static constexpr int NS = 2048;    // seq
static constexpr int ND = 1024;    // model dim
static constexpr int NH = 16;      // heads
static constexpr int HD = 64;      // head dim
static constexpr float QSCALE = 0.18033688011112042f;  // log2(e)/sqrt(64)

// async global->LDS, 16B per lane; LDS dest = wave-uniform base + lane*16
#define GL16(g, l)                                                             \
    __builtin_amdgcn_global_load_lds(                                          \
        (const __attribute__((address_space(1))) void*)(g),                    \
        (__attribute__((address_space(3))) void*)(l), 16, 0, 0)

// pack 2 f32 -> u32 of 2 bf16 (compiler fuses to v_cvt_pk_bf16_f32)
static __device__ __forceinline__ unsigned pk2(float a, float b) {
    union { __bf16 h[2]; unsigned u; } t;
    t.h[0] = (__bf16)a; t.h[1] = (__bf16)b;
    return t.u;
}

// ---------------- convert f32 -> bf16 (vectorized) ----------------
__global__ void k_conv(const float* __restrict__ in, bf16* __restrict__ out, int n) {
    int i = (blockIdx.x * blockDim.x + threadIdx.x) * 4;
    if (i < n) {
        float4 v = *reinterpret_cast<const float4*>(in + i);
        bf16* o = out + i;
        o[0] = (bf16)v.x; o[1] = (bf16)v.y; o[2] = (bf16)v.z; o[3] = (bf16)v.w;
    }
}

// ------------- transpose + convert: in[K][N] f32 -> out[N][K] bf16 -------------
__global__ void k_transconv(const float* __restrict__ in, bf16* __restrict__ out,
                            int K, int N) {
    __shared__ float tile[32][33];
    int k0 = blockIdx.y * 32, n0 = blockIdx.x * 32;
    int tx = threadIdx.x, ty = threadIdx.y;  // block (32,8)
    for (int j = 0; j < 32; j += 8)
        tile[ty + j][tx] = in[(long)(k0 + ty + j) * N + n0 + tx];
    __syncthreads();
    for (int j = 0; j < 32; j += 8)
        out[(long)(n0 + ty + j) * K + k0 + tx] = (bf16)tile[tx][ty + j];
}

// ======== GEMM-A: 256x256 tile, 8 waves (2M x 4N), 4 quadrant-phases/K-tile ===
// m201-template geometry. Per-wave out 128x64 (acc[8][4]). BK=64, LDS 128KB
// [buf][half]. Each wave stages ONLY the half-tiles it reads (8 gloads burst
// at K-tile entry -> vmcnt(8) with ~4 phases of landing slack). B-frags live
// in registers for the whole K-tile. Scatter epilogue to Q (scaled), K, Vt.
__global__ __launch_bounds__(512, 2) void k_gemmA(
    const bf16* __restrict__ A, const bf16* __restrict__ Bt,
    const float* __restrict__ bias,
    bf16* __restrict__ Qb, bf16* __restrict__ Kb, bf16* __restrict__ Vt,
    int M, int N, int Kd)
{
    constexpr int BK = 64;
    __shared__ __align__(16) bf16 As[2][2][128 * BK];   // [buf][half] 64 KB
    __shared__ __align__(16) bf16 Bs[2][2][128 * BK];   // [buf][half] 64 KB

    const int t = threadIdx.x;
    const int wid = t >> 6, lane = t & 63;
    const int wr = wid >> 2;            // 0..1  (M group: rows wr*128..+127)
    const int wc = wid & 3;             // 0..3  (N group: cols wc*64..+63)
    const int wcH = wc >> 1;            // B half this wave reads
    const int m0 = blockIdx.y * 256, n0 = blockIdx.x * 256;
    const int lrow = lane & 15, lhi = lane >> 4;

    // staging lane mapping (pre-swizzled source col, linear LDS dest)
    const int slr = lane >> 3;                     // row within 8-row unit
    const int scol = ((lane & 7) ^ slr) * 8;       // swizzled elem col
    const int arow = (wid & 3) * 32;               // A rows-in-half base (4 units x 8)
    const int bg = (wid & 1) | ((wid >> 2) << 1);  // B group idx among 4 stager waves
    const int brow = bg * 32;

    auto STAGE8 = [&](int buf, int kt) {
        const long kb = (long)kt * BK;
#pragma unroll
        for (int u = 0; u < 4; ++u)
            GL16(A + (long)(m0 + wr * 128 + arow + u * 8 + slr) * Kd + kb + scol,
                 &As[buf][wr][(arow + u * 8) * BK]);
#pragma unroll
        for (int u = 0; u < 4; ++u)
            GL16(Bt + (long)(n0 + wcH * 128 + brow + u * 8 + slr) * Kd + kb + scol,
                 &Bs[buf][wcH][(brow + u * 8) * BK]);
    };

    f32x4 acc[8][4] = {};
    const int nt = Kd >> 6;   // 16
    const int swz = (lrow & 7) << 4;
    int co[2];
#pragma unroll
    for (int kk = 0; kk < 2; ++kk)
        co[kk] = ((kk * 64 + lhi * 16) ^ swz) >> 1;   // elem offset in 64-elem row

    const bf16* asb;   // wave's A half base (const across loop)
    const bf16* bsb;

    STAGE8(0, 0);

    bf16x8 bfr[4][2];   // all 4 nj, held across the K-tile
    bf16x8 af[4][2];    // current mq's 4 mi

    for (int kt = 0; kt < nt; ++kt) {
        const int buf = kt & 1;
        if (kt + 1 < nt) {
            STAGE8(buf ^ 1, kt + 1);
            asm volatile("s_waitcnt vmcnt(8)" ::: "memory");  // kt's 8 landed
        } else {
            asm volatile("s_waitcnt vmcnt(0)" ::: "memory");
        }
        __builtin_amdgcn_s_barrier();
        __builtin_amdgcn_sched_barrier(0);
        asb = &As[buf][wr][0];
        bsb = &Bs[buf][wcH][0];

        // ---- phase 0: read B nj0,1 + A mi0..3 ; MFMA (mq0, nj0,1) ----
#pragma unroll
        for (int nj = 0; nj < 2; ++nj)
#pragma unroll
            for (int kk = 0; kk < 2; ++kk)
                bfr[nj][kk] = *reinterpret_cast<const bf16x8*>(
                    &bsb[((wc & 1) * 64 + nj * 16 + lrow) * BK + co[kk]]);
#pragma unroll
        for (int i = 0; i < 4; ++i)
#pragma unroll
            for (int kk = 0; kk < 2; ++kk)
                af[i][kk] = *reinterpret_cast<const bf16x8*>(
                    &asb[(i * 16 + lrow) * BK + co[kk]]);
        asm volatile("s_waitcnt lgkmcnt(0)" ::: "memory");
        __builtin_amdgcn_sched_barrier(0);
        __builtin_amdgcn_s_setprio(1);
#pragma unroll
        for (int kk = 0; kk < 2; ++kk)
#pragma unroll
            for (int i = 0; i < 4; ++i)
#pragma unroll
                for (int nj = 0; nj < 2; ++nj)
                    acc[i][nj] = __builtin_amdgcn_mfma_f32_16x16x32_bf16(
                        af[i][kk], bfr[nj][kk], acc[i][nj], 0, 0, 0);
        __builtin_amdgcn_s_setprio(0);
        __builtin_amdgcn_s_barrier();

        // ---- phase 1: read B nj2,3 ; MFMA (mq0, nj2,3) ----
#pragma unroll
        for (int nj = 2; nj < 4; ++nj)
#pragma unroll
            for (int kk = 0; kk < 2; ++kk)
                bfr[nj][kk] = *reinterpret_cast<const bf16x8*>(
                    &bsb[((wc & 1) * 64 + nj * 16 + lrow) * BK + co[kk]]);
        asm volatile("s_waitcnt lgkmcnt(0)" ::: "memory");
        __builtin_amdgcn_sched_barrier(0);
        __builtin_amdgcn_s_setprio(1);
#pragma unroll
        for (int kk = 0; kk < 2; ++kk)
#pragma unroll
            for (int i = 0; i < 4; ++i)
#pragma unroll
                for (int nj = 2; nj < 4; ++nj)
                    acc[i][nj] = __builtin_amdgcn_mfma_f32_16x16x32_bf16(
                        af[i][kk], bfr[nj][kk], acc[i][nj], 0, 0, 0);
        __builtin_amdgcn_s_setprio(0);
        __builtin_amdgcn_s_barrier();

        // ---- phase 2: read A mi4..7 ; MFMA (mq1, nj0,1) ----
#pragma unroll
        for (int i = 0; i < 4; ++i)
#pragma unroll
            for (int kk = 0; kk < 2; ++kk)
                af[i][kk] = *reinterpret_cast<const bf16x8*>(
                    &asb[(64 + i * 16 + lrow) * BK + co[kk]]);
        asm volatile("s_waitcnt lgkmcnt(0)" ::: "memory");
        __builtin_amdgcn_sched_barrier(0);
        __builtin_amdgcn_s_setprio(1);
#pragma unroll
        for (int kk = 0; kk < 2; ++kk)
#pragma unroll
            for (int i = 0; i < 4; ++i)
#pragma unroll
                for (int nj = 0; nj < 2; ++nj)
                    acc[4 + i][nj] = __builtin_amdgcn_mfma_f32_16x16x32_bf16(
                        af[i][kk], bfr[nj][kk], acc[4 + i][nj], 0, 0, 0);
        __builtin_amdgcn_s_setprio(0);
        __builtin_amdgcn_s_barrier();

        // ---- phase 3: MFMA (mq1, nj2,3) ----
        __builtin_amdgcn_s_setprio(1);
#pragma unroll
        for (int kk = 0; kk < 2; ++kk)
#pragma unroll
            for (int i = 0; i < 4; ++i)
#pragma unroll
                for (int nj = 2; nj < 4; ++nj)
                    acc[4 + i][nj] = __builtin_amdgcn_mfma_f32_16x16x32_bf16(
                        af[i][kk], bfr[nj][kk], acc[4 + i][nj], 0, 0, 0);
        __builtin_amdgcn_s_setprio(0);
        __builtin_amdgcn_s_barrier();
    }

    // epilogue: scatter to Q (scaled) / K / Vt
#pragma unroll
    for (int nj = 0; nj < 4; ++nj) {
        int col = n0 + wc * 64 + nj * 16 + lrow;
        float bv = bias[col];
        int which = col >> 10;          // 0:q 1:k 2:v
        int rem = col & 1023;
        int h = rem >> 6, d = rem & 63;
#pragma unroll
        for (int mi = 0; mi < 8; ++mi) {
            int mbase = m0 + wr * 128 + mi * 16 + lhi * 4;
#pragma unroll
            for (int r = 0; r < 4; ++r) {
                int row = mbase + r;
                int bb = row >> 11, s = row & 2047;
                long bh = bb * NH + h;
                float v = acc[mi][nj][r] + bv;
                if (which == 0)      Qb[(bh * NS + s) * HD + d] = (bf16)(v * QSCALE);
                else if (which == 1) Kb[(bh * NS + s) * HD + d] = (bf16)v;
                else                 Vt[(bh * HD + d) * NS + s] = (bf16)v;
            }
        }
    }
}

// ======== GEMM-B: 128x128 2-phase + counted vmcnt (r8 known-good), f32 out ====
__global__ __launch_bounds__(256, 2) void k_gemmB(
    const bf16* __restrict__ A, const bf16* __restrict__ Bt,
    const float* __restrict__ bias, float* __restrict__ O,
    int M, int N, int Kd)
{
    constexpr int BM = 128, BN = 128, BK = 64;
    __shared__ __align__(16) bf16 As[2][BM * BK];
    __shared__ __align__(16) bf16 Bs[2][BN * BK];

    const int t = threadIdx.x;
    const int wid = t >> 6, lane = t & 63;
    const int wm = wid >> 1, wn = wid & 1;
    const int m0 = blockIdx.y * BM, n0 = blockIdx.x * BN;
    const int lrow = lane & 15, lhi = lane >> 4;

    const int srow0 = wid * 32 + (lane >> 3);
    const int scol = ((lane & 7) ^ (lane >> 3)) * 8;
    const bf16* ag = A + (long)(m0 + srow0) * Kd + scol;
    const bf16* bg = Bt + (long)(n0 + srow0) * Kd + scol;

    auto STAGE = [&](int buf_, int k0_) {
#pragma unroll
        for (int c = 0; c < 4; ++c) {
            GL16(ag + (long)(c * 8) * Kd + k0_, &As[buf_][(wid * 32 + c * 8) * BK]);
            GL16(bg + (long)(c * 8) * Kd + k0_, &Bs[buf_][(wid * 32 + c * 8) * BK]);
        }
    };

    f32x4 acc[4][4] = {};
    const int nt = Kd >> 6;
    const int swzr = (lrow & 7) << 4;
    int co[2];
#pragma unroll
    for (int kk = 0; kk < 2; ++kk)
        co[kk] = ((kk * 64 + lhi * 16) ^ swzr) >> 1;

    STAGE(0, 0);
    int cur = 0;
    for (int tix = 0; tix < nt; ++tix) {
        if (tix + 1 < nt) {
            STAGE(cur ^ 1, (tix + 1) * BK);
            asm volatile("s_waitcnt vmcnt(8)" ::: "memory");
        } else {
            asm volatile("s_waitcnt vmcnt(0)" ::: "memory");
        }
        __builtin_amdgcn_s_barrier();
        __builtin_amdgcn_sched_barrier(0);

        bf16x8 af[2][4], bfr[2][4];
#pragma unroll
        for (int kk = 0; kk < 2; ++kk)
#pragma unroll
            for (int i = 0; i < 4; ++i) {
                af[kk][i]  = *reinterpret_cast<const bf16x8*>(
                    &As[cur][(wm * 64 + i * 16 + lrow) * BK + co[kk]]);
                bfr[kk][i] = *reinterpret_cast<const bf16x8*>(
                    &Bs[cur][(wn * 64 + i * 16 + lrow) * BK + co[kk]]);
            }
        __builtin_amdgcn_s_setprio(1);
#pragma unroll
        for (int kk = 0; kk < 2; ++kk)
#pragma unroll
            for (int i = 0; i < 4; ++i)
#pragma unroll
                for (int j = 0; j < 4; ++j)
                    acc[i][j] = __builtin_amdgcn_mfma_f32_16x16x32_bf16(
                        af[kk][i], bfr[kk][j], acc[i][j], 0, 0, 0);
        __builtin_amdgcn_s_setprio(0);
        __builtin_amdgcn_s_barrier();
        cur ^= 1;
    }

#pragma unroll
    for (int j = 0; j < 4; ++j) {
        int col = n0 + wn * 64 + j * 16 + lrow;
        float bv = bias[col];
#pragma unroll
        for (int i = 0; i < 4; ++i) {
            int mbase = m0 + wm * 64 + i * 16 + lhi * 4;
#pragma unroll
            for (int r = 0; r < 4; ++r)
                O[(long)(mbase + r) * N + col] = acc[i][j][r] + bv;
        }
    }
}

// ---------------- flash attention v5: V-hoist + counted vmcnt ----------------
__global__ __launch_bounds__(256, 4) void k_attn(
    const bf16* __restrict__ Qb, const bf16* __restrict__ Kb,
    const bf16* __restrict__ Vt, bf16* __restrict__ Ao)
{
    constexpr int KB = 64;
    constexpr int NT = NS / KB;   // 32 tiles
    __shared__ __align__(16) bf16 Ks[2][KB * HD];   // row=key, 128B, swizzled
    __shared__ __align__(16) bf16 Vs[2][HD * KB];   // row=d,   128B, swizzled
    __shared__ __align__(16) bf16 Ps[4 * 16 * 64];  // per-wave 16q x 64k, swizzled

    const int t = threadIdx.x;
    const int wid = t >> 6, lane = t & 63;
    const int lrow = lane & 15, lhi = lane >> 4;

    const int flat = blockIdx.y * gridDim.x + blockIdx.x;
    const int n = (flat & 7) * 128 + (flat >> 3);
    const int bh = n >> 4;
    const int qw = (n & 15) * 128 + wid * 32;   // wave's 32 q rows

    const bf16* Qg = Qb + ((long)bh * NS + qw) * HD;
    const bf16* Kg = Kb + (long)bh * NS * HD;
    const bf16* Vg = Vt + (long)bh * HD * NS;

    bf16x8 qf[2][2];
#pragma unroll
    for (int qfr = 0; qfr < 2; ++qfr)
#pragma unroll
        for (int c = 0; c < 2; ++c)
            qf[qfr][c] = *reinterpret_cast<const bf16x8*>(
                Qg + (long)(qfr * 16 + lrow) * HD + c * 32 + lhi * 8);

    f32x4 of[2][4] = {};
    float lsum[2] = {0.f, 0.f};

    const int gsr = lane >> 3;
    const int gsc = ((lane & 7) ^ gsr) * 8;
    auto STAGE = [&](int buf, int kb) {
#pragma unroll
        for (int c = 0; c < 2; ++c) {
            const int rb = wid * 16 + c * 8;
            GL16(Kg + (long)(kb + rb + gsr) * HD + gsc, &Ks[buf][rb * 64]);
            GL16(Vg + (long)(rb + gsr) * NS + kb + gsc, &Vs[buf][rb * 64]);
        }
    };

    const int rsw = (lrow & 7) << 4;
    bf16* psw = &Ps[wid * 1024 + lrow * 64];

    auto COMPUTE = [&](int b_) {
        f32x4 st[2][4] = {};
        __builtin_amdgcn_s_setprio(1);
#pragma unroll
        for (int j = 0; j < 4; ++j)
#pragma unroll
            for (int c = 0; c < 2; ++c) {
                bf16x8 kf = *reinterpret_cast<const bf16x8*>(
                    &Ks[b_][(j * 16 + lrow) * 64 + (((c * 64 + lhi * 16) ^ rsw) >> 1)]);
#pragma unroll
                for (int qfr = 0; qfr < 2; ++qfr)
                    st[qfr][j] = __builtin_amdgcn_mfma_f32_16x16x32_bf16(
                        kf, qf[qfr][c], st[qfr][j], 0, 0, 0);
            }
        __builtin_amdgcn_s_setprio(0);

        bf16x8 pfr[2][2];
#pragma unroll
        for (int qfr = 0; qfr < 2; ++qfr) {
#pragma unroll
            for (int j = 0; j < 4; ++j) {
                float e0 = __builtin_amdgcn_exp2f(st[qfr][j][0]);
                float e1 = __builtin_amdgcn_exp2f(st[qfr][j][1]);
                float e2 = __builtin_amdgcn_exp2f(st[qfr][j][2]);
                float e3 = __builtin_amdgcn_exp2f(st[qfr][j][3]);
                lsum[qfr] += (e0 + e1) + (e2 + e3);
                u32x2 w; w[0] = pk2(e0, e1); w[1] = pk2(e2, e3);
                *reinterpret_cast<u32x2*>(
                    reinterpret_cast<char*>(psw) + (((j * 32 + lhi * 8) ^ rsw))) = w;
            }
            asm volatile("" ::: "memory");
#pragma unroll
            for (int chunk = 0; chunk < 2; ++chunk)
                pfr[qfr][chunk] = *reinterpret_cast<const bf16x8*>(
                    reinterpret_cast<char*>(psw) + ((chunk * 64 + lhi * 16) ^ rsw));
            asm volatile("" ::: "memory");
        }

        __builtin_amdgcn_s_setprio(1);
#pragma unroll
        for (int chunk = 0; chunk < 2; ++chunk)
#pragma unroll
            for (int f = 0; f < 4; ++f) {
                bf16x8 vf = *reinterpret_cast<const bf16x8*>(
                    &Vs[b_][(f * 16 + lrow) * 64 +
                            (((chunk * 64 + lhi * 16) ^ rsw) >> 1)]);
#pragma unroll
                for (int qfr = 0; qfr < 2; ++qfr)
                    of[qfr][f] = __builtin_amdgcn_mfma_f32_16x16x32_bf16(
                        pfr[qfr][chunk], vf, of[qfr][f], 0, 0, 0);
            }
        __builtin_amdgcn_s_setprio(0);
    };

    STAGE(0, 0);
    int cur = 0;
    for (int it = 0; it < NT; ++it) {
        if (it + 1 < NT) {
            STAGE(cur ^ 1, (it + 1) * KB);
            asm volatile("s_waitcnt vmcnt(4)" ::: "memory");
        } else {
            asm volatile("s_waitcnt vmcnt(0)" ::: "memory");
        }
        __builtin_amdgcn_s_barrier();
        __builtin_amdgcn_sched_barrier(0);
        COMPUTE(cur);
        __builtin_amdgcn_s_barrier();
        cur ^= 1;
    }

#pragma unroll
    for (int qfr = 0; qfr < 2; ++qfr) {
        lsum[qfr] += __shfl_xor(lsum[qfr], 16);
        lsum[qfr] += __shfl_xor(lsum[qfr], 32);
    }

    const int bb = bh >> 4, h = bh & 15;
#pragma unroll
    for (int qfr = 0; qfr < 2; ++qfr) {
#pragma unroll
        for (int r = 0; r < 4; ++r) {
            float inv = 1.0f / __shfl(lsum[qfr], 4 * lhi + r);
            int s = qw + qfr * 16 + 4 * lhi + r;
#pragma unroll
            for (int f = 0; f < 4; ++f)
                Ao[((long)bb * NS + s) * ND + h * HD + f * 16 + lrow] =
                    (bf16)(of[qfr][f][r] * inv);
        }
    }
}

// ---------------- launch ----------------
extern "C" void kernel_launch(void* const* d_in, const int* in_sizes, int n_in,
                              void* d_out, int out_size, void* d_ws, size_t ws_size,
                              hipStream_t stream) {
    const float* x    = (const float*)d_in[0];
    const float* Wqkv = (const float*)d_in[1];
    const float* bqkv = (const float*)d_in[2];
    const float* Wout = (const float*)d_in[3];
    const float* bout = (const float*)d_in[4];
    float* out = (float*)d_out;

    char* ws = (char*)d_ws;
    bf16* Xb  = (bf16*)(ws);                         // 16.78 MB
    bf16* Wqt = (bf16*)(ws + 16777216);              //  6.29 MB
    bf16* Wot = (bf16*)(ws + 23068672);              //  2.10 MB
    bf16* Qb  = (bf16*)(ws + 25165824);              // 16.78 MB
    bf16* Kb  = (bf16*)(ws + 41943040);              // 16.78 MB
    bf16* Vt  = (bf16*)(ws + 58720256);              // 16.78 MB
    bf16* Ab  = (bf16*)(ws + 75497472);              // 16.78 MB  (total ~92 MB)

    k_conv<<<dim3(8192), dim3(256), 0, stream>>>(x, Xb, NB * NS * ND);
    k_transconv<<<dim3(96, 32), dim3(32, 8), 0, stream>>>(Wqkv, Wqt, ND, 3 * ND);
    k_transconv<<<dim3(32, 32), dim3(32, 8), 0, stream>>>(Wout, Wot, ND, ND);

    k_gemmA<<<dim3(12, 32), dim3(512), 0, stream>>>(
        Xb, Wqt, bqkv, Qb, Kb, Vt, NB * NS, 3 * ND, ND);

    k_attn<<<dim3(16, 64), dim3(256), 0, stream>>>(Qb, Kb, Vt, Ab);

    k_gemmB<<<dim3(8, 64), dim3(256), 0, stream>>>(
        Ab, Wot, bout, out, NB * NS, ND, ND);
}